// Round 16
// baseline (146.206 us; speedup 1.0000x reference)
//
#include <hip/hip_runtime.h>

#define NH   32
#define NHK  8
#define D    128
#define KB   64
#define NT   128   // S / KB

typedef float f32x16 __attribute__((ext_vector_type(16)));
typedef short bf16x8 __attribute__((ext_vector_type(8)));
typedef unsigned int uint4v __attribute__((ext_vector_type(4)));

__device__ __forceinline__ unsigned cvtpk(float lo, float hi) {
  unsigned r;
  asm("v_cvt_pk_bf16_f32 %0, %1, %2" : "=v"(r) : "v"(lo), "v"(hi));
  return r;
}
__device__ __forceinline__ void gload16(const void* g, void* l) {
  __builtin_amdgcn_global_load_lds(
      (__attribute__((address_space(1))) void*)g,
      (__attribute__((address_space(3))) void*)l, 16, 0, 0);
}

// Paired-row swizzled indices (<=2-way on b128 reads).
__device__ __forceinline__ int kidx(int j, int col) {
  return (((j >> 1) << 8) + ((j & 1) << 7) + col) ^ (((j >> 1) & 15) << 3);
}
__device__ __forceinline__ int vidx(int d, int j) {
  return (((d >> 1) << 7) + ((d & 1) << 6) + j) ^ (((d >> 1) & 15) << 3);
}

// ---- prep: K -> bf16 tiled+swizzled; V -> V^T bf16 tiled+swizzled ----
__global__ __launch_bounds__(256)
void prep_kv(const float* __restrict__ kg, const float* __restrict__ vg,
             short* __restrict__ kpre, short* __restrict__ vpre)
{
  int blk = blockIdx.x;
  int tid = threadIdx.x;
  bool isV = blk >= (NHK * NT);
  int lb   = isV ? blk - NHK * NT : blk;
  int hk   = lb >> 7;
  int t    = lb & 127;
  if (!isV) {
    int j  = tid >> 2;
    int dq = (tid & 3) * 32;
    const float* kp = kg + ((size_t)(t*KB + j) * NHK + hk) * D + dq;
    short* dst = kpre + (((size_t)(hk*NT + t)) << 13);
    #pragma unroll
    for (int c = 0; c < 4; ++c) {
      float4 a  = *(const float4*)(kp + c*8);
      float4 b2 = *(const float4*)(kp + c*8 + 4);
      uint4v u;
      u[0] = cvtpk(a.x, a.y);   u[1] = cvtpk(a.z, a.w);
      u[2] = cvtpk(b2.x, b2.y); u[3] = cvtpk(b2.z, b2.w);
      *(uint4v*)&dst[kidx(j, dq + c*8)] = u;
    }
  } else {
    int d0 = (tid & 31) * 4;
    int j0 = (tid >> 5) * 8;
    float tv[8][4];
    #pragma unroll
    for (int r = 0; r < 8; ++r) {
      float4 x = *(const float4*)(vg + ((size_t)(t*KB + j0 + r) * NHK + hk) * D + d0);
      tv[r][0]=x.x; tv[r][1]=x.y; tv[r][2]=x.z; tv[r][3]=x.w;
    }
    short* dst = vpre + (((size_t)(hk*NT + t)) << 13);
    #pragma unroll
    for (int c = 0; c < 4; ++c) {
      int d = d0 + c;
      uint4v u;
      u[0] = cvtpk(tv[0][c], tv[1][c]);
      u[1] = cvtpk(tv[2][c], tv[3][c]);
      u[2] = cvtpk(tv[4][c], tv[5][c]);
      u[3] = cvtpk(tv[6][c], tv[7][c]);
      *(uint4v*)&dst[vidx(d, j0)] = u;
    }
  }
}

// ---- main: 8-wave block = 4 GQA heads x 2 row-halves over SAME 64 q-rows;
//      one shared pair-staging stream; identical tile range -> zero skip-idle ----
__global__ __launch_bounds__(512, 2)
void swa_fwd(const float* __restrict__ qg, const short* __restrict__ kpre,
             const short* __restrict__ vpre, float* __restrict__ og)
{
  __shared__ __align__(16) short lds_k[2][KB * D];   // pair of sub-tiles, 32 KB
  __shared__ __align__(16) short lds_v[2][KB * D];   // pair of sub-tiles, 32 KB

  const int tid  = threadIdx.x;
  const int lane = tid & 63;
  const int w    = tid >> 6;      // 0..7
  const int hs   = w & 3;         // head within GQA group
  const int rh   = w >> 2;        // row half (0..1)
  const int il   = lane & 31;
  const int half = lane >> 5;

  // 1024 blocks: xcd (= b%8) owns one kv-head; within: qb
  int b   = blockIdx.x;
  int lidx = (b & 7) * 128 + (b >> 3);
  int hk  = lidx >> 7;
  int qb  = lidx & 127;           // 64-row q block index
  int h   = hk * 4 + hs;
  int qs  = qb * 64;

  const float qscale = 0.088388347648318447f * 1.4426950408889634f;

  // Q fragments (B-operand for swapped QK^T), pre-scaled
  bf16x8 qf[8];
  {
    const float* qp = qg + ((size_t)(qs + 32*rh + il) * NH + h) * D + half * 8;
    #pragma unroll
    for (int ks = 0; ks < 8; ++ks) {
      float4 a = *(const float4*)(qp + ks*16);
      float4 c = *(const float4*)(qp + ks*16 + 4);
      uint4v u;
      u[0] = cvtpk(a.x*qscale, a.y*qscale);
      u[1] = cvtpk(a.z*qscale, a.w*qscale);
      u[2] = cvtpk(c.x*qscale, c.y*qscale);
      u[3] = cvtpk(c.z*qscale, c.w*qscale);
      qf[ks] = __builtin_bit_cast(bf16x8, u);
    }
  }

  f32x16 acc_o[4];
  #pragma unroll
  for (int dt = 0; dt < 4; ++dt)
    #pragma unroll
    for (int r = 0; r < 16; ++r) acc_o[dt][r] = 0.0f;

  // per-lane partial softmax denominator (no max tracking; pure sum)
  float l0 = 0.0f, l1 = 0.0f, l2 = 0.0f, l3 = 0.0f;

  int t_lo = qb - 8; if (t_lo < 0) t_lo = 0;
  const int T_lo = t_lo >> 1;
  const int T_hi = qb >> 1;
  const int iw_min = qs + 32*rh;

  const short* gkb = kpre + (((size_t)hk * NT) << 13);
  const short* gvb = vpre + (((size_t)hk * NT) << 13);
  const int lo2 = w * 2048;          // shorts; wave's 4 KB chunk of the 32 KB pair
  const int go2 = lo2 + lane * 8;    // +16 B per lane

  for (int T = T_lo; T <= T_hi; ++T) {
    // ---- stage tile pair (2T, 2T+1): each wave copies 1/8 ----
    {
      const short* gk = gkb + ((size_t)T << 14);
      const short* gv = gvb + ((size_t)T << 14);
      #pragma unroll
      for (int i = 0; i < 4; ++i) gload16(gk + go2 + i*512, &lds_k[0][0] + lo2 + i*512);
      #pragma unroll
      for (int i = 0; i < 4; ++i) gload16(gv + go2 + i*512, &lds_v[0][0] + lo2 + i*512);
    }
    asm volatile("s_waitcnt vmcnt(0)" ::: "memory");
    __builtin_amdgcn_s_barrier();
    __builtin_amdgcn_sched_barrier(0);

    #pragma unroll
    for (int st = 0; st < 2; ++st) {
      const int t  = 2*T + st;
      const int kt = t * KB;
      const short* lk = &lds_k[st][0];
      const short* lv = &lds_v[st][0];

      bool skip = (kt > iw_min + 31) || (kt + KB - 1 < iw_min - 511);
      if (!skip) {
        f32x16 acc_s[2];
        #pragma unroll
        for (int mt = 0; mt < 2; ++mt)
          #pragma unroll
          for (int r = 0; r < 16; ++r) acc_s[mt][r] = 0.0f;

        __builtin_amdgcn_s_setprio(1);
        #pragma unroll
        for (int ks = 0; ks < 8; ++ks) {
          #pragma unroll
          for (int mt = 0; mt < 2; ++mt) {
            int jrow = mt*32 + il;
            bf16x8 a = *(const bf16x8*)&lk[kidx(jrow, ks*16 + half*8)];
            acc_s[mt] = __builtin_amdgcn_mfma_f32_32x32x16_bf16(a, qf[ks], acc_s[mt], 0, 0, 0);
          }
        }
        __builtin_amdgcn_s_setprio(0);

        bool do_causal = (kt + KB - 1 > iw_min);
        bool do_window = (kt < iw_min + 31 - 511);
        if (do_causal || do_window) {
          int base0 = kt - iw_min - il + 4*half;
          #pragma unroll
          for (int mt = 0; mt < 2; ++mt)
            #pragma unroll
            for (int r = 0; r < 16; ++r) {
              int delta = base0 + 32*mt + (r & 3) + 8*(r >> 2); // j - i
              if ((do_causal && delta > 0) || (do_window && delta < -511))
                acc_s[mt][r] = -1e30f;
            }
        }

        // p = exp2(S) directly — no max subtraction (scale-invariant in O)
        #pragma unroll
        for (int mt = 0; mt < 2; ++mt) {
          float p[16];
          #pragma unroll
          for (int r = 0; r < 16; ++r)
            p[r] = __builtin_amdgcn_exp2f(acc_s[mt][r]);
          l0 += p[0] + p[4];  l1 += p[1] + p[5];
          l2 += p[2] + p[6];  l3 += p[3] + p[7];
          l0 += p[8] + p[12]; l1 += p[9] + p[13];
          l2 += p[10]+ p[14]; l3 += p[11]+ p[15];

          unsigned pkw[8];
          #pragma unroll
          for (int hb = 0; hb < 2; ++hb) {
            int bs = hb * 8;
            unsigned X1 = cvtpk(p[bs+0], p[bs+1]);
            unsigned X2 = cvtpk(p[bs+2], p[bs+3]);
            unsigned Y1 = cvtpk(p[bs+4], p[bs+5]);
            unsigned Y2 = cvtpk(p[bs+6], p[bs+7]);
            asm("v_permlane32_swap_b32 %0, %1" : "+v"(X1), "+v"(Y1));
            asm("v_permlane32_swap_b32 %0, %1" : "+v"(X2), "+v"(Y2));
            pkw[hb*4 + 0] = X1; pkw[hb*4 + 1] = X2;
            pkw[hb*4 + 2] = Y1; pkw[hb*4 + 3] = Y2;
          }
          __builtin_amdgcn_s_setprio(1);
          #pragma unroll
          for (int ksl = 0; ksl < 2; ++ksl) {
            int ks = mt*2 + ksl;
            uint4v pu;
            pu[0] = pkw[ksl*4+0]; pu[1] = pkw[ksl*4+1];
            pu[2] = pkw[ksl*4+2]; pu[3] = pkw[ksl*4+3];
            bf16x8 pb = __builtin_bit_cast(bf16x8, pu);
            #pragma unroll
            for (int dt = 0; dt < 4; ++dt) {
              int d = dt*32 + il;
              bf16x8 a = *(const bf16x8*)&lv[vidx(d, ks*16 + half*8)];
              acc_o[dt] = __builtin_amdgcn_mfma_f32_32x32x16_bf16(a, pb, acc_o[dt], 0, 0, 0);
            }
          }
          __builtin_amdgcn_s_setprio(0);
        }
      }
    }
    if (T < T_hi) __builtin_amdgcn_s_barrier();  // protect pair before next stage
  }

  // epilogue: one cross-half reduce for l, then normalize
  float l_lane = (l0 + l1) + (l2 + l3);
  float l_tot  = l_lane + __shfl_xor(l_lane, 32);
  float inv_l  = 1.0f / l_tot;
  const size_t orow = ((size_t)(qs + 32*rh + il) * NH + h) * D;
  #pragma unroll
  for (int dt = 0; dt < 4; ++dt)
    #pragma unroll
    for (int rg = 0; rg < 4; ++rg) {
      float4 o;
      o.x = acc_o[dt][rg*4+0] * inv_l;
      o.y = acc_o[dt][rg*4+1] * inv_l;
      o.z = acc_o[dt][rg*4+2] * inv_l;
      o.w = acc_o[dt][rg*4+3] * inv_l;
      *(float4*)(og + orow + dt*32 + 8*rg + 4*half) = o;
    }
}

// ---- fallback (ws too small): self-contained, same no-max math ----
__global__ __launch_bounds__(256, 2)
void swa_fwd_fb(const float* __restrict__ qg, const float* __restrict__ kg,
                const float* __restrict__ vg, float* __restrict__ og)
{
  __shared__ __align__(16) short lds_k[KB * D];
  __shared__ __align__(16) short lds_v[D * KB];

  const int tid  = threadIdx.x;
  const int lane = tid & 63;
  const int w    = tid >> 6;
  const int il   = lane & 31;
  const int half = lane >> 5;

  int b    = blockIdx.x;
  int lidx = (b & 7) * 256 + (b >> 3);
  int hk   = lidx >> 8;
  int rem  = lidx & 255;
  int bq   = rem >> 2;
  int h    = hk * 4 + (rem & 3);
  int qs   = bq * 128;

  const float qscale = 0.088388347648318447f * 1.4426950408889634f;

  bf16x8 qf[8];
  {
    const float* qp = qg + ((size_t)(qs + 32*w + il) * NH + h) * D + half * 8;
    #pragma unroll
    for (int ks = 0; ks < 8; ++ks) {
      float4 a = *(const float4*)(qp + ks*16);
      float4 c = *(const float4*)(qp + ks*16 + 4);
      uint4v u;
      u[0] = cvtpk(a.x*qscale, a.y*qscale);
      u[1] = cvtpk(a.z*qscale, a.w*qscale);
      u[2] = cvtpk(c.x*qscale, c.y*qscale);
      u[3] = cvtpk(c.z*qscale, c.w*qscale);
      qf[ks] = __builtin_bit_cast(bf16x8, u);
    }
  }

  f32x16 acc_o[4];
  #pragma unroll
  for (int dt = 0; dt < 4; ++dt)
    #pragma unroll
    for (int r = 0; r < 16; ++r) acc_o[dt][r] = 0.0f;

  float l0 = 0.0f, l1 = 0.0f, l2 = 0.0f, l3 = 0.0f;

  int t_lo = 2*bq - 8; if (t_lo < 0) t_lo = 0;
  int t_hi = 2*bq + 1;
  const int iw_min = qs + 32*w;

  for (int t = t_lo; t <= t_hi; ++t) {
    const int kt = t * KB;
    {
      int j  = tid >> 2;
      int dq = (tid & 3) * 32;
      const float* kp = kg + ((size_t)(kt + j) * NHK + hk) * D + dq;
      #pragma unroll
      for (int c = 0; c < 4; ++c) {
        float4 a  = *(const float4*)(kp + c*8);
        float4 d2 = *(const float4*)(kp + c*8 + 4);
        uint4v u;
        u[0] = cvtpk(a.x, a.y);   u[1] = cvtpk(a.z, a.w);
        u[2] = cvtpk(d2.x, d2.y); u[3] = cvtpk(d2.z, d2.w);
        *(uint4v*)&lds_k[kidx(j, dq + c*8)] = u;
      }
    }
    {
      int d0 = (tid & 31) * 4;
      int j0 = (tid >> 5) * 8;
      float tv[8][4];
      #pragma unroll
      for (int r = 0; r < 8; ++r) {
        float4 x = *(const float4*)(vg + ((size_t)(kt + j0 + r) * NHK + hk) * D + d0);
        tv[r][0]=x.x; tv[r][1]=x.y; tv[r][2]=x.z; tv[r][3]=x.w;
      }
      #pragma unroll
      for (int c = 0; c < 4; ++c) {
        int d = d0 + c;
        uint4v u;
        u[0] = cvtpk(tv[0][c], tv[1][c]);
        u[1] = cvtpk(tv[2][c], tv[3][c]);
        u[2] = cvtpk(tv[4][c], tv[5][c]);
        u[3] = cvtpk(tv[6][c], tv[7][c]);
        *(uint4v*)&lds_v[vidx(d, j0)] = u;
      }
    }
    __syncthreads();

    bool skip = (kt > iw_min + 31) || (kt + KB - 1 < iw_min - 511);
    if (!skip) {
      f32x16 acc_s[2];
      #pragma unroll
      for (int mt = 0; mt < 2; ++mt)
        #pragma unroll
        for (int r = 0; r < 16; ++r) acc_s[mt][r] = 0.0f;

      #pragma unroll
      for (int ks = 0; ks < 8; ++ks) {
        #pragma unroll
        for (int mt = 0; mt < 2; ++mt) {
          int jrow = mt*32 + il;
          bf16x8 a = *(const bf16x8*)&lds_k[kidx(jrow, ks*16 + half*8)];
          acc_s[mt] = __builtin_amdgcn_mfma_f32_32x32x16_bf16(a, qf[ks], acc_s[mt], 0, 0, 0);
        }
      }

      bool do_causal = (kt + KB - 1 > iw_min);
      bool do_window = (kt < iw_min + 31 - 511);
      if (do_causal || do_window) {
        int base0 = kt - iw_min - il + 4*half;
        #pragma unroll
        for (int mt = 0; mt < 2; ++mt)
          #pragma unroll
          for (int r = 0; r < 16; ++r) {
            int delta = base0 + 32*mt + (r & 3) + 8*(r >> 2);
            if ((do_causal && delta > 0) || (do_window && delta < -511))
              acc_s[mt][r] = -1e30f;
          }
      }

      #pragma unroll
      for (int mt = 0; mt < 2; ++mt) {
        float p[16];
        #pragma unroll
        for (int r = 0; r < 16; ++r)
          p[r] = __builtin_amdgcn_exp2f(acc_s[mt][r]);
        l0 += p[0] + p[4];  l1 += p[1] + p[5];
        l2 += p[2] + p[6];  l3 += p[3] + p[7];
        l0 += p[8] + p[12]; l1 += p[9] + p[13];
        l2 += p[10]+ p[14]; l3 += p[11]+ p[15];

        unsigned pkw[8];
        #pragma unroll
        for (int hb = 0; hb < 2; ++hb) {
          int bs = hb * 8;
          unsigned X1 = cvtpk(p[bs+0], p[bs+1]);
          unsigned X2 = cvtpk(p[bs+2], p[bs+3]);
          unsigned Y1 = cvtpk(p[bs+4], p[bs+5]);
          unsigned Y2 = cvtpk(p[bs+6], p[bs+7]);
          asm("v_permlane32_swap_b32 %0, %1" : "+v"(X1), "+v"(Y1));
          asm("v_permlane32_swap_b32 %0, %1" : "+v"(X2), "+v"(Y2));
          pkw[hb*4 + 0] = X1; pkw[hb*4 + 1] = X2;
          pkw[hb*4 + 2] = Y1; pkw[hb*4 + 3] = Y2;
        }
        #pragma unroll
        for (int ksl = 0; ksl < 2; ++ksl) {
          int ks = mt*2 + ksl;
          uint4v pu;
          pu[0] = pkw[ksl*4+0]; pu[1] = pkw[ksl*4+1];
          pu[2] = pkw[ksl*4+2]; pu[3] = pkw[ksl*4+3];
          bf16x8 pb = __builtin_bit_cast(bf16x8, pu);
          #pragma unroll
          for (int dt = 0; dt < 4; ++dt) {
            int d = dt*32 + il;
            bf16x8 a = *(const bf16x8*)&lds_v[vidx(d, ks*16 + half*8)];
            acc_o[dt] = __builtin_amdgcn_mfma_f32_32x32x16_bf16(a, pb, acc_o[dt], 0, 0, 0);
          }
        }
      }
    }
    __syncthreads();
  }

  float l_lane = (l0 + l1) + (l2 + l3);
  float l_tot  = l_lane + __shfl_xor(l_lane, 32);
  float inv_l  = 1.0f / l_tot;
  const size_t orow = ((size_t)(qs + 32*w + il) * NH + h) * D;
  #pragma unroll
  for (int dt = 0; dt < 4; ++dt)
    #pragma unroll
    for (int rg = 0; rg < 4; ++rg) {
      float4 o;
      o.x = acc_o[dt][rg*4+0] * inv_l;
      o.y = acc_o[dt][rg*4+1] * inv_l;
      o.z = acc_o[dt][rg*4+2] * inv_l;
      o.w = acc_o[dt][rg*4+3] * inv_l;
      *(float4*)(og + orow + dt*32 + 8*rg + 4*half) = o;
    }
}

extern "C" void kernel_launch(void* const* d_in, const int* in_sizes, int n_in,
                              void* d_out, int out_size, void* d_ws, size_t ws_size,
                              hipStream_t stream) {
  const float* q = (const float*)d_in[0];
  const float* k = (const float*)d_in[1];
  const float* v = (const float*)d_in[2];
  float* o = (float*)d_out;
  const size_t per = (size_t)NHK * NT * KB * D;          // elements per prepped tensor
  const size_t need = 2 * per * sizeof(short);           // 33,554,432 bytes
  if (ws_size >= need) {
    short* kpre = (short*)d_ws;
    short* vpre = kpre + per;
    hipLaunchKernelGGL(prep_kv, dim3(2 * NHK * NT), dim3(256), 0, stream, k, v, kpre, vpre);
    hipLaunchKernelGGL(swa_fwd, dim3(1024), dim3(512), 0, stream, q, kpre, vpre, o);
  } else {
    hipLaunchKernelGGL(swa_fwd_fb, dim3(2048), dim3(256), 0, stream, q, k, v, o);
  }
}

// Round 17
// 135.687 us; speedup vs baseline: 1.0775x; 1.0775x over previous
//
#include <hip/hip_runtime.h>

#define NH   32
#define NHK  8
#define D    128
#define QB   128
#define KB   64
#define NT   128   // S / KB

typedef float f32x16 __attribute__((ext_vector_type(16)));
typedef short bf16x8 __attribute__((ext_vector_type(8)));
typedef unsigned int uint4v __attribute__((ext_vector_type(4)));

__device__ __forceinline__ unsigned cvtpk(float lo, float hi) {
  unsigned r;
  asm("v_cvt_pk_bf16_f32 %0, %1, %2" : "=v"(r) : "v"(lo), "v"(hi));
  return r;
}
__device__ __forceinline__ void gload16(const void* g, void* l) {
  __builtin_amdgcn_global_load_lds(
      (__attribute__((address_space(1))) void*)g,
      (__attribute__((address_space(3))) void*)l, 16, 0, 0);
}

// Paired-row swizzled indices (<=2-way on b128 reads).
// K tile [64 j][128 col]: idx = (j>>1)*256 + (j&1)*128 + col, XOR ((j>>1)&15)<<3
__device__ __forceinline__ int kidx(int j, int col) {
  return (((j >> 1) << 8) + ((j & 1) << 7) + col) ^ (((j >> 1) & 15) << 3);
}
// V^T tile [128 d][64 j]: idx = (d>>1)*128 + (d&1)*64 + j, XOR ((d>>1)&15)<<3
__device__ __forceinline__ int vidx(int d, int j) {
  return (((d >> 1) << 7) + ((d & 1) << 6) + j) ^ (((d >> 1) & 15) << 3);
}

// ---- prep: K -> bf16 tiled+swizzled; V -> V^T bf16 tiled+swizzled ----
__global__ __launch_bounds__(256)
void prep_kv(const float* __restrict__ kg, const float* __restrict__ vg,
             short* __restrict__ kpre, short* __restrict__ vpre)
{
  int blk = blockIdx.x;
  int tid = threadIdx.x;
  bool isV = blk >= (NHK * NT);
  int lb   = isV ? blk - NHK * NT : blk;
  int hk   = lb >> 7;
  int t    = lb & 127;
  if (!isV) {
    int j  = tid >> 2;
    int dq = (tid & 3) * 32;
    const float* kp = kg + ((size_t)(t*KB + j) * NHK + hk) * D + dq;
    short* dst = kpre + (((size_t)(hk*NT + t)) << 13);
    #pragma unroll
    for (int c = 0; c < 4; ++c) {
      float4 a  = *(const float4*)(kp + c*8);
      float4 b2 = *(const float4*)(kp + c*8 + 4);
      uint4v u;
      u[0] = cvtpk(a.x, a.y);   u[1] = cvtpk(a.z, a.w);
      u[2] = cvtpk(b2.x, b2.y); u[3] = cvtpk(b2.z, b2.w);
      *(uint4v*)&dst[kidx(j, dq + c*8)] = u;
    }
  } else {
    int d0 = (tid & 31) * 4;
    int j0 = (tid >> 5) * 8;
    float tv[8][4];
    #pragma unroll
    for (int r = 0; r < 8; ++r) {
      float4 x = *(const float4*)(vg + ((size_t)(t*KB + j0 + r) * NHK + hk) * D + d0);
      tv[r][0]=x.x; tv[r][1]=x.y; tv[r][2]=x.z; tv[r][3]=x.w;
    }
    short* dst = vpre + (((size_t)(hk*NT + t)) << 13);
    #pragma unroll
    for (int c = 0; c < 4; ++c) {
      int d = d0 + c;
      uint4v u;
      u[0] = cvtpk(tv[0][c], tv[1][c]);
      u[1] = cvtpk(tv[2][c], tv[3][c]);
      u[2] = cvtpk(tv[4][c], tv[5][c]);
      u[3] = cvtpk(tv[6][c], tv[7][c]);
      *(uint4v*)&dst[vidx(d, j0)] = u;
    }
  }
}

// ---- main: R10 structure, tile-PAIR staging (half the barriers/drains) ----
__global__ __launch_bounds__(256, 2)
void swa_fwd(const float* __restrict__ qg, const short* __restrict__ kpre,
             const short* __restrict__ vpre, float* __restrict__ og)
{
  __shared__ __align__(16) short lds_k[2][KB * D];   // pair of sub-tiles, 32 KB
  __shared__ __align__(16) short lds_v[2][KB * D];   // pair of sub-tiles, 32 KB

  const int tid  = threadIdx.x;
  const int lane = tid & 63;
  const int w    = tid >> 6;
  const int il   = lane & 31;
  const int half = lane >> 5;

  int b    = blockIdx.x;
  int lidx = (b & 7) * 256 + (b >> 3);
  int hk   = lidx >> 8;
  int rem  = lidx & 255;
  int bq   = rem >> 2;
  int h    = hk * 4 + (rem & 3);
  int qs   = bq * QB;

  const float qscale = 0.088388347648318447f * 1.4426950408889634f;

  // Q fragments (B-operand for swapped QK^T), pre-scaled
  bf16x8 qf[8];
  {
    const float* qp = qg + ((size_t)(qs + 32*w + il) * NH + h) * D + half * 8;
    #pragma unroll
    for (int ks = 0; ks < 8; ++ks) {
      float4 a = *(const float4*)(qp + ks*16);
      float4 c = *(const float4*)(qp + ks*16 + 4);
      uint4v u;
      u[0] = cvtpk(a.x*qscale, a.y*qscale);
      u[1] = cvtpk(a.z*qscale, a.w*qscale);
      u[2] = cvtpk(c.x*qscale, c.y*qscale);
      u[3] = cvtpk(c.z*qscale, c.w*qscale);
      qf[ks] = __builtin_bit_cast(bf16x8, u);
    }
  }

  f32x16 acc_o[4];
  #pragma unroll
  for (int dt = 0; dt < 4; ++dt)
    #pragma unroll
    for (int r = 0; r < 16; ++r) acc_o[dt][r] = 0.0f;

  // per-lane partial softmax denominator (no max tracking; pure sum)
  float l0 = 0.0f, l1 = 0.0f, l2 = 0.0f, l3 = 0.0f;

  int t_lo = 2*bq - 8; if (t_lo < 0) t_lo = 0;   // even by construction
  const int T_lo = t_lo >> 1;
  const int T_hi = bq;                           // covers t up to 2*bq+1
  const int iw_min = qs + 32*w;

  const short* gkb = kpre + (((size_t)hk * NT) << 13);
  const short* gvb = vpre + (((size_t)hk * NT) << 13);
  const int lo2 = w * 4096;          // shorts; wave's 8 KB chunk of the 32 KB pair
  const int go2 = lo2 + lane * 8;    // +16 B per lane

  for (int T = T_lo; T <= T_hi; ++T) {
    // ---- stage tile pair (2T, 2T+1): contiguous 32 KB per tensor ----
    {
      const short* gk = gkb + ((size_t)T << 14);
      const short* gv = gvb + ((size_t)T << 14);
      #pragma unroll
      for (int i = 0; i < 8; ++i) gload16(gk + go2 + i*512, &lds_k[0][0] + lo2 + i*512);
      #pragma unroll
      for (int i = 0; i < 8; ++i) gload16(gv + go2 + i*512, &lds_v[0][0] + lo2 + i*512);
    }
    asm volatile("s_waitcnt vmcnt(0)" ::: "memory");
    __builtin_amdgcn_s_barrier();
    __builtin_amdgcn_sched_barrier(0);

    #pragma unroll
    for (int st = 0; st < 2; ++st) {
      const int t  = 2*T + st;
      const int kt = t * KB;
      const short* lk = &lds_k[st][0];
      const short* lv = &lds_v[st][0];

      bool skip = (kt > iw_min + 31) || (kt + KB - 1 < iw_min - 511);
      if (!skip) {
        f32x16 acc_s[2];
        #pragma unroll
        for (int mt = 0; mt < 2; ++mt)
          #pragma unroll
          for (int r = 0; r < 16; ++r) acc_s[mt][r] = 0.0f;

        __builtin_amdgcn_s_setprio(1);
        #pragma unroll
        for (int ks = 0; ks < 8; ++ks) {
          #pragma unroll
          for (int mt = 0; mt < 2; ++mt) {
            int jrow = mt*32 + il;
            bf16x8 a = *(const bf16x8*)&lk[kidx(jrow, ks*16 + half*8)];
            acc_s[mt] = __builtin_amdgcn_mfma_f32_32x32x16_bf16(a, qf[ks], acc_s[mt], 0, 0, 0);
          }
        }
        __builtin_amdgcn_s_setprio(0);

        bool do_causal = (kt + KB - 1 > iw_min);
        bool do_window = (kt < iw_min + 31 - 511);
        if (do_causal || do_window) {
          int base0 = kt - iw_min - il + 4*half;
          #pragma unroll
          for (int mt = 0; mt < 2; ++mt)
            #pragma unroll
            for (int r = 0; r < 16; ++r) {
              int delta = base0 + 32*mt + (r & 3) + 8*(r >> 2); // j - i
              if ((do_causal && delta > 0) || (do_window && delta < -511))
                acc_s[mt][r] = -1e30f;
            }
        }

        // p = exp2(S) directly — no max subtraction (scale-invariant in O)
        #pragma unroll
        for (int mt = 0; mt < 2; ++mt) {
          float p[16];
          #pragma unroll
          for (int r = 0; r < 16; ++r)
            p[r] = __builtin_amdgcn_exp2f(acc_s[mt][r]);
          l0 += p[0] + p[4];  l1 += p[1] + p[5];
          l2 += p[2] + p[6];  l3 += p[3] + p[7];
          l0 += p[8] + p[12]; l1 += p[9] + p[13];
          l2 += p[10]+ p[14]; l3 += p[11]+ p[15];

          unsigned pkw[8];
          #pragma unroll
          for (int hb = 0; hb < 2; ++hb) {
            int bs = hb * 8;
            unsigned X1 = cvtpk(p[bs+0], p[bs+1]);
            unsigned X2 = cvtpk(p[bs+2], p[bs+3]);
            unsigned Y1 = cvtpk(p[bs+4], p[bs+5]);
            unsigned Y2 = cvtpk(p[bs+6], p[bs+7]);
            asm("v_permlane32_swap_b32 %0, %1" : "+v"(X1), "+v"(Y1));
            asm("v_permlane32_swap_b32 %0, %1" : "+v"(X2), "+v"(Y2));
            pkw[hb*4 + 0] = X1; pkw[hb*4 + 1] = X2;
            pkw[hb*4 + 2] = Y1; pkw[hb*4 + 3] = Y2;
          }
          __builtin_amdgcn_s_setprio(1);
          #pragma unroll
          for (int ksl = 0; ksl < 2; ++ksl) {
            int ks = mt*2 + ksl;
            uint4v pu;
            pu[0] = pkw[ksl*4+0]; pu[1] = pkw[ksl*4+1];
            pu[2] = pkw[ksl*4+2]; pu[3] = pkw[ksl*4+3];
            bf16x8 pb = __builtin_bit_cast(bf16x8, pu);
            #pragma unroll
            for (int dt = 0; dt < 4; ++dt) {
              int d = dt*32 + il;
              bf16x8 a = *(const bf16x8*)&lv[vidx(d, ks*16 + half*8)];
              acc_o[dt] = __builtin_amdgcn_mfma_f32_32x32x16_bf16(a, pb, acc_o[dt], 0, 0, 0);
            }
          }
          __builtin_amdgcn_s_setprio(0);
        }
      }
    }
    if (T < T_hi) __builtin_amdgcn_s_barrier();  // protect pair before next stage
  }

  // epilogue: one cross-half reduce for l, then normalize
  float l_lane = (l0 + l1) + (l2 + l3);
  float l_tot  = l_lane + __shfl_xor(l_lane, 32);
  float inv_l  = 1.0f / l_tot;
  const size_t orow = ((size_t)(qs + 32*w + il) * NH + h) * D;
  #pragma unroll
  for (int dt = 0; dt < 4; ++dt)
    #pragma unroll
    for (int rg = 0; rg < 4; ++rg) {
      float4 o;
      o.x = acc_o[dt][rg*4+0] * inv_l;
      o.y = acc_o[dt][rg*4+1] * inv_l;
      o.z = acc_o[dt][rg*4+2] * inv_l;
      o.w = acc_o[dt][rg*4+3] * inv_l;
      *(float4*)(og + orow + dt*32 + 8*rg + 4*half) = o;
    }
}

// ---- fallback (ws too small): self-contained, same no-max math ----
__global__ __launch_bounds__(256, 2)
void swa_fwd_fb(const float* __restrict__ qg, const float* __restrict__ kg,
                const float* __restrict__ vg, float* __restrict__ og)
{
  __shared__ __align__(16) short lds_k[KB * D];
  __shared__ __align__(16) short lds_v[D * KB];

  const int tid  = threadIdx.x;
  const int lane = tid & 63;
  const int w    = tid >> 6;
  const int il   = lane & 31;
  const int half = lane >> 5;

  int b    = blockIdx.x;
  int lidx = (b & 7) * 256 + (b >> 3);
  int hk   = lidx >> 8;
  int rem  = lidx & 255;
  int bq   = rem >> 2;
  int h    = hk * 4 + (rem & 3);
  int qs   = bq * 128;

  const float qscale = 0.088388347648318447f * 1.4426950408889634f;

  bf16x8 qf[8];
  {
    const float* qp = qg + ((size_t)(qs + 32*w + il) * NH + h) * D + half * 8;
    #pragma unroll
    for (int ks = 0; ks < 8; ++ks) {
      float4 a = *(const float4*)(qp + ks*16);
      float4 c = *(const float4*)(qp + ks*16 + 4);
      uint4v u;
      u[0] = cvtpk(a.x*qscale, a.y*qscale);
      u[1] = cvtpk(a.z*qscale, a.w*qscale);
      u[2] = cvtpk(c.x*qscale, c.y*qscale);
      u[3] = cvtpk(c.z*qscale, c.w*qscale);
      qf[ks] = __builtin_bit_cast(bf16x8, u);
    }
  }

  f32x16 acc_o[4];
  #pragma unroll
  for (int dt = 0; dt < 4; ++dt)
    #pragma unroll
    for (int r = 0; r < 16; ++r) acc_o[dt][r] = 0.0f;

  float l0 = 0.0f, l1 = 0.0f, l2 = 0.0f, l3 = 0.0f;

  int t_lo = 2*bq - 8; if (t_lo < 0) t_lo = 0;
  int t_hi = 2*bq + 1;
  const int iw_min = qs + 32*w;

  for (int t = t_lo; t <= t_hi; ++t) {
    const int kt = t * KB;
    {
      int j  = tid >> 2;
      int dq = (tid & 3) * 32;
      const float* kp = kg + ((size_t)(kt + j) * NHK + hk) * D + dq;
      #pragma unroll
      for (int c = 0; c < 4; ++c) {
        float4 a  = *(const float4*)(kp + c*8);
        float4 d2 = *(const float4*)(kp + c*8 + 4);
        uint4v u;
        u[0] = cvtpk(a.x, a.y);   u[1] = cvtpk(a.z, a.w);
        u[2] = cvtpk(d2.x, d2.y); u[3] = cvtpk(d2.z, d2.w);
        *(uint4v*)&lds_k[kidx(j, dq + c*8)] = u;
      }
    }
    {
      int d0 = (tid & 31) * 4;
      int j0 = (tid >> 5) * 8;
      float tv[8][4];
      #pragma unroll
      for (int r = 0; r < 8; ++r) {
        float4 x = *(const float4*)(vg + ((size_t)(kt + j0 + r) * NHK + hk) * D + d0);
        tv[r][0]=x.x; tv[r][1]=x.y; tv[r][2]=x.z; tv[r][3]=x.w;
      }
      #pragma unroll
      for (int c = 0; c < 4; ++c) {
        int d = d0 + c;
        uint4v u;
        u[0] = cvtpk(tv[0][c], tv[1][c]);
        u[1] = cvtpk(tv[2][c], tv[3][c]);
        u[2] = cvtpk(tv[4][c], tv[5][c]);
        u[3] = cvtpk(tv[6][c], tv[7][c]);
        *(uint4v*)&lds_v[vidx(d, j0)] = u;
      }
    }
    __syncthreads();

    bool skip = (kt > iw_min + 31) || (kt + KB - 1 < iw_min - 511);
    if (!skip) {
      f32x16 acc_s[2];
      #pragma unroll
      for (int mt = 0; mt < 2; ++mt)
        #pragma unroll
        for (int r = 0; r < 16; ++r) acc_s[mt][r] = 0.0f;

      #pragma unroll
      for (int ks = 0; ks < 8; ++ks) {
        #pragma unroll
        for (int mt = 0; mt < 2; ++mt) {
          int jrow = mt*32 + il;
          bf16x8 a = *(const bf16x8*)&lds_k[kidx(jrow, ks*16 + half*8)];
          acc_s[mt] = __builtin_amdgcn_mfma_f32_32x32x16_bf16(a, qf[ks], acc_s[mt], 0, 0, 0);
        }
      }

      bool do_causal = (kt + KB - 1 > iw_min);
      bool do_window = (kt < iw_min + 31 - 511);
      if (do_causal || do_window) {
        int base0 = kt - iw_min - il + 4*half;
        #pragma unroll
        for (int mt = 0; mt < 2; ++mt)
          #pragma unroll
          for (int r = 0; r < 16; ++r) {
            int delta = base0 + 32*mt + (r & 3) + 8*(r >> 2);
            if ((do_causal && delta > 0) || (do_window && delta < -511))
              acc_s[mt][r] = -1e30f;
          }
      }

      #pragma unroll
      for (int mt = 0; mt < 2; ++mt) {
        float p[16];
        #pragma unroll
        for (int r = 0; r < 16; ++r)
          p[r] = __builtin_amdgcn_exp2f(acc_s[mt][r]);
        l0 += p[0] + p[4];  l1 += p[1] + p[5];
        l2 += p[2] + p[6];  l3 += p[3] + p[7];
        l0 += p[8] + p[12]; l1 += p[9] + p[13];
        l2 += p[10]+ p[14]; l3 += p[11]+ p[15];

        unsigned pkw[8];
        #pragma unroll
        for (int hb = 0; hb < 2; ++hb) {
          int bs = hb * 8;
          unsigned X1 = cvtpk(p[bs+0], p[bs+1]);
          unsigned X2 = cvtpk(p[bs+2], p[bs+3]);
          unsigned Y1 = cvtpk(p[bs+4], p[bs+5]);
          unsigned Y2 = cvtpk(p[bs+6], p[bs+7]);
          asm("v_permlane32_swap_b32 %0, %1" : "+v"(X1), "+v"(Y1));
          asm("v_permlane32_swap_b32 %0, %1" : "+v"(X2), "+v"(Y2));
          pkw[hb*4 + 0] = X1; pkw[hb*4 + 1] = X2;
          pkw[hb*4 + 2] = Y1; pkw[hb*4 + 3] = Y2;
        }
        #pragma unroll
        for (int ksl = 0; ksl < 2; ++ksl) {
          int ks = mt*2 + ksl;
          uint4v pu;
          pu[0] = pkw[ksl*4+0]; pu[1] = pkw[ksl*4+1];
          pu[2] = pkw[ksl*4+2]; pu[3] = pkw[ksl*4+3];
          bf16x8 pb = __builtin_bit_cast(bf16x8, pu);
          #pragma unroll
          for (int dt = 0; dt < 4; ++dt) {
            int d = dt*32 + il;
            bf16x8 a = *(const bf16x8*)&lds_v[vidx(d, ks*16 + half*8)];
            acc_o[dt] = __builtin_amdgcn_mfma_f32_32x32x16_bf16(a, pb, acc_o[dt], 0, 0, 0);
          }
        }
      }
    }
    __syncthreads();
  }

  float l_lane = (l0 + l1) + (l2 + l3);
  float l_tot  = l_lane + __shfl_xor(l_lane, 32);
  float inv_l  = 1.0f / l_tot;
  const size_t orow = ((size_t)(qs + 32*w + il) * NH + h) * D;
  #pragma unroll
  for (int dt = 0; dt < 4; ++dt)
    #pragma unroll
    for (int rg = 0; rg < 4; ++rg) {
      float4 o;
      o.x = acc_o[dt][rg*4+0] * inv_l;
      o.y = acc_o[dt][rg*4+1] * inv_l;
      o.z = acc_o[dt][rg*4+2] * inv_l;
      o.w = acc_o[dt][rg*4+3] * inv_l;
      *(float4*)(og + orow + dt*32 + 8*rg + 4*half) = o;
    }
}

extern "C" void kernel_launch(void* const* d_in, const int* in_sizes, int n_in,
                              void* d_out, int out_size, void* d_ws, size_t ws_size,
                              hipStream_t stream) {
  const float* q = (const float*)d_in[0];
  const float* k = (const float*)d_in[1];
  const float* v = (const float*)d_in[2];
  float* o = (float*)d_out;
  const size_t per = (size_t)NHK * NT * KB * D;          // elements per prepped tensor
  const size_t need = 2 * per * sizeof(short);           // 33,554,432 bytes
  if (ws_size >= need) {
    short* kpre = (short*)d_ws;
    short* vpre = kpre + per;
    hipLaunchKernelGGL(prep_kv, dim3(2 * NHK * NT), dim3(256), 0, stream, k, v, kpre, vpre);
    hipLaunchKernelGGL(swa_fwd, dim3(2048), dim3(256), 0, stream, q, kpre, vpre, o);
  } else {
    hipLaunchKernelGGL(swa_fwd_fb, dim3(2048), dim3(256), 0, stream, q, k, v, o);
  }
}